// Round 12
// baseline (187.516 us; speedup 1.0000x reference)
//
#include <hip/hip_runtime.h>
#include <hip/hip_fp16.h>

#define N_NODES 50000
#define IN_F    128
#define HID_F   128
#define OUT_F   64
#define E_EDGES 800000

// Fine buckets: 16 rows = one aggregation block; consumer counting-sorts its
// ~256 edges in LDS then register-accumulates.  Measured lessons:
//  - r5: per-row global scatter = 64B/edge writeback (94us). Bin runs stay
//    bucket-contiguous.
//  - r9: LDS f32 atomicAdd scatter = 102M ds_add = 588us. Registers only.
//  - r7: deeper batches lose to VGPR/occupancy; widen loads instead.
//  - r10: in-consumer sort beats separate sort dispatch (181->178).
#define RPB   16
#define NBUCK ((N_NODES + RPB - 1) / RPB)            // 3125
#define BCAP  384                                    // mean 256, +8 sigma
#define BIN_T   512
#define BIN_EPT 16
#define BIN_EPB (BIN_T * BIN_EPT)                    // 8192 edges per block
#define BIN_NB  ((E_EDGES + BIN_EPB - 1) / BIN_EPB)  // 98
#define B1_EPT  8                                    // bin1: low-VGPR variant
#define B1_EPB  (256 * B1_EPT)                       // 2048 edges per block
#define B1_NB   ((E_EDGES + B1_EPB - 1) / B1_EPB)    // 391
#define G0_NB   ((N_NODES + 127) / 128)              // 391 gemm0 blocks
#define HP      (HID_F + 8)                          // ht stride (272B, 16-aligned)

typedef _Float16 half8 __attribute__((ext_vector_type(8)));
typedef _Float16 hv4   __attribute__((ext_vector_type(4)));
typedef float    floatx4 __attribute__((ext_vector_type(4)));

// ---------------- Prep: zero gfill + convert W0/W1 to fp16 transposed -------
__global__ __launch_bounds__(256) void prep_kernel(const float* __restrict__ W0,
                                                   const float* __restrict__ W1,
                                                   __half* __restrict__ wt0,
                                                   __half* __restrict__ wt1,
                                                   int* __restrict__ gfill) {
    int tid = blockIdx.x * 256 + threadIdx.x;
    if (tid < IN_F * HID_F) {               // wt0[n][k] = W0[k][n], 128x128
        int k = tid >> 7, n = tid & 127;
        wt0[n * IN_F + k] = __float2half(W0[tid]);
    }
    if (tid < HID_F * OUT_F) {              // wt1[n][k] = W1[k][n], 128x64
        int k = tid / OUT_F, n = tid % OUT_F;
        wt1[n * HID_F + k] = __float2half(W1[tid]);
    }
    if (tid < 2 * NBUCK) gfill[tid] = 0;
}

// ---------------- Dispatch 1: bin graph0 (y=0) + layer-0 GEMM (y=1) --------
union D1Lds {
    int lhist[NBUCK];                    // 12.5 KB (lbase overwrites in place)
    _Float16 ws[HID_F * (IN_F + 8)];     // 34.8 KB (dominates)
};

__global__ __launch_bounds__(BIN_T) void bin0_gemm_kernel(
        const int* __restrict__ row0, const int* __restrict__ col0, const float* __restrict__ val0,
        int* __restrict__ gfill, int2* __restrict__ bcv0,
        const float* __restrict__ x, const __half* __restrict__ wt0,
        __half* __restrict__ sup0, int M) {
    __shared__ D1Lds lds;
    const int tid = threadIdx.x;

    if (blockIdx.y == 0) {
        // ---------------- bucket binning graph 0 ----------------
        if (blockIdx.x >= BIN_NB) return;
        for (int i = tid; i < NBUCK; i += BIN_T) lds.lhist[i] = 0;
        __syncthreads();

        int rnk[BIN_EPT], bkt[BIN_EPT], cl[BIN_EPT], rw[BIN_EPT];
        float vl[BIN_EPT];
        const int e0 = blockIdx.x * BIN_EPB;
#pragma unroll
        for (int i = 0; i < BIN_EPT; ++i) {
            const int e = e0 + i * BIN_T + tid;
            bkt[i] = -1;
            if (e < E_EDGES) {
                const int r = row0[e];
                rw[i] = r; cl[i] = col0[e]; vl[i] = val0[e];
                bkt[i] = r >> 4;
                rnk[i] = atomicAdd(&lds.lhist[bkt[i]], 1);
            }
        }
        __syncthreads();
        for (int i = tid; i < NBUCK; i += BIN_T) {     // lhist -> lbase in place
            const int c = lds.lhist[i];
            lds.lhist[i] = c ? atomicAdd(&gfill[i], c) : 0;
        }
        __syncthreads();
#pragma unroll
        for (int i = 0; i < BIN_EPT; ++i) {
            if (bkt[i] >= 0) {
                const int pos = lds.lhist[bkt[i]] + rnk[i];
                if (pos < BCAP)
                    bcv0[(long)bkt[i] * BCAP + pos] =
                        make_int2(((rw[i] & (RPB - 1)) << 16) | cl[i], __float_as_int(vl[i]));
            }
        }
    } else {
        // ---------------- layer-0 GEMM: 128 rows per block ----------
        constexpr int KP = IN_F + 8;
        constexpr int NT = HID_F / 16;
        for (int c = tid; c < HID_F * (IN_F / 8); c += BIN_T) {
            const int n = c / (IN_F / 8), ko = (c % (IN_F / 8)) * 8;
            *(half8*)&lds.ws[n * KP + ko] = *(const half8*)(wt0 + n * IN_F + ko);
        }
        __syncthreads();

        const int wv = tid >> 6, lane = tid & 63;
        const int quad = lane >> 4, l16 = lane & 15;
        const int rowb = blockIdx.x * 128 + wv * 16;
        const int arow = rowb + l16;

        floatx4 acc[NT] = {};
#pragma unroll
        for (int ks = 0; ks < IN_F; ks += 32) {
            half8 af = {};
            if (arow < M) {
                const float4* p = (const float4*)(x + (long)arow * IN_F + ks + quad * 8);
                float4 u = p[0], w = p[1];
                af[0] = (_Float16)u.x; af[1] = (_Float16)u.y;
                af[2] = (_Float16)u.z; af[3] = (_Float16)u.w;
                af[4] = (_Float16)w.x; af[5] = (_Float16)w.y;
                af[6] = (_Float16)w.z; af[7] = (_Float16)w.w;
            }
#pragma unroll
            for (int t = 0; t < NT; ++t) {
                half8 bf = *(const half8*)&lds.ws[(t * 16 + l16) * KP + ks + quad * 8];
                acc[t] = __builtin_amdgcn_mfma_f32_16x16x32_f16(af, bf, acc[t], 0, 0, 0);
            }
        }
#pragma unroll
        for (int t = 0; t < NT; ++t) {
            const int col = t * 16 + l16;
#pragma unroll
            for (int i = 0; i < 4; ++i) {
                const int row = rowb + quad * 4 + i;
                if (row < M) sup0[(long)row * HID_F + col] = __float2half(acc[t][i]);
            }
        }
    }
}

// ---------------- Dispatch 2: agg+relu+gemm1 (y=0) || bin graph1 (y=1) -----
// agg phase-1: half-wave per edge, hv4 (8B) gathers -> 16 rows in flight per
// wave at 8-deep batch (2x MLP of r10 at ~same VGPR; r7 lesson honored).
// bin1 rides along (EPT=8, 40 VGPRs) so its ~10us leaves the critical path.
union D2Lds {
    int lhist[NBUCK];                  // 12.5 KB (bin1 path)
    struct {
        int2 sbuf[BCAP];               // 3 KB sorted edges
        int  cur[RPB];
        int  st[RPB + 1];
        _Float16 ht[16 * HP];          // 4.4 KB
    } a;                               // 7.6 KB (agg path)
};

__global__ __launch_bounds__(256) void agg_bin1_kernel(
        int* __restrict__ gfill, const int2* __restrict__ bcv0, int2* __restrict__ bcv1,
        const int* __restrict__ row1, const int* __restrict__ col1, const float* __restrict__ val1,
        const __half* __restrict__ sup, const float* __restrict__ bias,
        const __half* __restrict__ wt1, __half* __restrict__ sup1) {
    __shared__ D2Lds lds;
    const int tid = threadIdx.x;

    if (blockIdx.y == 1) {
        // ---------------- bucket binning graph 1 (256 thr, EPT=8) ----------
        if (blockIdx.x >= B1_NB) return;
        int* gf = gfill + NBUCK;
        for (int i = tid; i < NBUCK; i += 256) lds.lhist[i] = 0;
        __syncthreads();

        int rnk[B1_EPT], bkt[B1_EPT], cl[B1_EPT], rw[B1_EPT];
        float vl[B1_EPT];
        const int e0 = blockIdx.x * B1_EPB;
#pragma unroll
        for (int i = 0; i < B1_EPT; ++i) {
            const int e = e0 + i * 256 + tid;
            bkt[i] = -1;
            if (e < E_EDGES) {
                const int r = row1[e];
                rw[i] = r; cl[i] = col1[e]; vl[i] = val1[e];
                bkt[i] = r >> 4;
                rnk[i] = atomicAdd(&lds.lhist[bkt[i]], 1);
            }
        }
        __syncthreads();
        for (int i = tid; i < NBUCK; i += 256) {       // lhist -> lbase in place
            const int c = lds.lhist[i];
            lds.lhist[i] = c ? atomicAdd(&gf[i], c) : 0;
        }
        __syncthreads();
#pragma unroll
        for (int i = 0; i < B1_EPT; ++i) {
            if (bkt[i] >= 0) {
                const int pos = lds.lhist[bkt[i]] + rnk[i];
                if (pos < BCAP)
                    bcv1[(long)bkt[i] * BCAP + pos] =
                        make_int2(((rw[i] & (RPB - 1)) << 16) | cl[i], __float_as_int(vl[i]));
            }
        }
        return;
    }

    // ---------------- agg path ----------------
    const int wv   = tid >> 6;
    const int lane = tid & 63;
    const int eh   = lane >> 5;
    const int li   = lane & 31;
    const int b    = blockIdx.x;
    const int cnt  = min(gfill[b], BCAP);
    const int2* eb = bcv0 + (long)b * BCAP;

    // ---- LDS counting sort by local row ----
    int2 ed[2]; int rnk2[2];
    if (tid < RPB) lds.a.cur[tid] = 0;
    __syncthreads();
#pragma unroll
    for (int k = 0; k < 2; ++k) {
        const int e = tid + k * 256;
        if (e < cnt) {
            ed[k] = eb[e];
            rnk2[k] = atomicAdd(&lds.a.cur[ed[k].x >> 16], 1);
        }
    }
    __syncthreads();
    if (tid == 0) {
        int s = 0;
#pragma unroll
        for (int i = 0; i < RPB; ++i) { lds.a.st[i] = s; s += lds.a.cur[i]; }
        lds.a.st[RPB] = s;
    }
    __syncthreads();
#pragma unroll
    for (int k = 0; k < 2; ++k) {
        const int e = tid + k * 256;
        if (e < cnt) lds.a.sbuf[lds.a.st[ed[k].x >> 16] + rnk2[k]] = ed[k];
    }
    __syncthreads();

    // ---- Phase 1: wave wv -> rows wv*4..+3; half-waves split even/odd edges;
    //      each lane owns 4 features, hv4 8B gathers (16 rows in flight/wave)
#pragma unroll
    for (int i = 0; i < 4; ++i) {
        const int r  = wv * 4 + i;
        const int s0 = lds.a.st[r], s1 = lds.a.st[r + 1];
        float a0, a1, a2, a3;
        if (eh == 0) {
            a0 = bias[li * 4];     a1 = bias[li * 4 + 1];
            a2 = bias[li * 4 + 2]; a3 = bias[li * 4 + 3];
        } else a0 = a1 = a2 = a3 = 0.f;
        for (int j = s0; j < s1; j += 16) {
            int   pr[8];
            float v[8];
#pragma unroll
            for (int q = 0; q < 8; ++q) {              // broadcast LDS reads
                const int idx = j + 2 * q + eh;
                if (idx < s1) {
                    int2 e2 = lds.a.sbuf[idx];
                    pr[q] = e2.x & 0xFFFF;
                    v[q]  = __int_as_float(e2.y);
                } else { pr[q] = 0; v[q] = 0.f; }
            }
            hv4 s8[8];
#pragma unroll
            for (int q = 0; q < 8; ++q)                // 8x 8B gathers in flight
                s8[q] = *(const hv4*)(sup + (long)pr[q] * HID_F + li * 4);
#pragma unroll
            for (int q = 0; q < 8; ++q) {
                a0 += v[q] * (float)s8[q][0];
                a1 += v[q] * (float)s8[q][1];
                a2 += v[q] * (float)s8[q][2];
                a3 += v[q] * (float)s8[q][3];
            }
        }
        a0 += __shfl_xor(a0, 32, 64);
        a1 += __shfl_xor(a1, 32, 64);
        a2 += __shfl_xor(a2, 32, 64);
        a3 += __shfl_xor(a3, 32, 64);
        if (eh == 0) {
            hv4 h;
            h[0] = (_Float16)(a0 > 0.f ? a0 : 0.f);
            h[1] = (_Float16)(a1 > 0.f ? a1 : 0.f);
            h[2] = (_Float16)(a2 > 0.f ? a2 : 0.f);
            h[3] = (_Float16)(a3 > 0.f ? a3 : 0.f);
            *(hv4*)&lds.a.ht[r * HP + li * 4] = h;
        }
    }
    __syncthreads();

    // ---- Phase 2: 16x64 gemm1 tile, wave wv -> cols wv*16..+15 ----
    const int quad = lane >> 4, l16 = lane & 15;
    floatx4 oacc = {};
#pragma unroll
    for (int ks = 0; ks < HID_F; ks += 32) {
        half8 af = *(const half8*)&lds.a.ht[l16 * HP + ks + quad * 8];
        half8 bf = *(const half8*)(wt1 + (long)(wv * 16 + l16) * HID_F + ks + quad * 8);
        oacc = __builtin_amdgcn_mfma_f32_16x16x32_f16(af, bf, oacc, 0, 0, 0);
    }
    const int r0 = b * 16;
#pragma unroll
    for (int i = 0; i < 4; ++i) {
        const int row = r0 + quad * 4 + i;
        sup1[(long)row * OUT_F + wv * 16 + l16] = __float2half(oacc[i]);
    }
}

// ---------------- SpMM layer 1: LDS sort + half-wave register aggregate ----
__global__ __launch_bounds__(256) void spmm_l1_kernel(const int* __restrict__ gfill,
                                                      const int2* __restrict__ bcv,
                                                      const __half* __restrict__ sup,
                                                      const float* __restrict__ bias,
                                                      float* __restrict__ out) {
    __shared__ int2 sbuf[BCAP];
    __shared__ int  cur[RPB];
    __shared__ int  st[RPB + 1];
    const int tid  = threadIdx.x;
    const int wv   = tid >> 6;
    const int lane = tid & 63;
    const int b    = blockIdx.x;
    const int cnt  = min(gfill[NBUCK + b], BCAP);
    const int2* eb = bcv + (long)b * BCAP;
    const int eh = lane >> 5;
    const int li = lane & 31;
    const int f0 = li * 2;

    // ---- LDS counting sort ----
    int2 ed[2]; int rnk[2];
    if (tid < RPB) cur[tid] = 0;
    __syncthreads();
#pragma unroll
    for (int k = 0; k < 2; ++k) {
        const int e = tid + k * 256;
        if (e < cnt) {
            ed[k] = eb[e];
            rnk[k] = atomicAdd(&cur[ed[k].x >> 16], 1);
        }
    }
    __syncthreads();
    if (tid == 0) {
        int s = 0;
#pragma unroll
        for (int i = 0; i < RPB; ++i) { st[i] = s; s += cur[i]; }
        st[RPB] = s;
    }
    __syncthreads();
#pragma unroll
    for (int k = 0; k < 2; ++k) {
        const int e = tid + k * 256;
        if (e < cnt) sbuf[st[ed[k].x >> 16] + rnk[k]] = ed[k];
    }
    __syncthreads();

    // ---- wave wv -> rows wv*4..+3; half-waves split even/odd edges ----
#pragma unroll
    for (int i = 0; i < 4; ++i) {
        const int r  = wv * 4 + i;
        const int s0 = st[r], s1 = st[r + 1];
        float acc0 = eh ? 0.f : bias[f0];
        float acc1 = eh ? 0.f : bias[f0 + 1];
        for (int j = s0; j < s1; j += 16) {
            int   pr[8];
            float v[8];
#pragma unroll
            for (int q = 0; q < 8; ++q) {
                const int idx = j + 2 * q + eh;
                if (idx < s1) {
                    int2 e2 = sbuf[idx];
                    pr[q] = e2.x & 0xFFFF;
                    v[q]  = __int_as_float(e2.y);
                } else { pr[q] = 0; v[q] = 0.f; }
            }
            __half2 s8[8];
#pragma unroll
            for (int q = 0; q < 8; ++q)
                s8[q] = *(const __half2*)(sup + (long)pr[q] * OUT_F + f0);
#pragma unroll
            for (int q = 0; q < 8; ++q) {
                float2 g = __half22float2(s8[q]);
                acc0 += v[q] * g.x; acc1 += v[q] * g.y;
            }
        }
        acc0 += __shfl_xor(acc0, 32, 64);
        acc1 += __shfl_xor(acc1, 32, 64);
        if (eh == 0) {
            const int row = b * 16 + r;
            *(float2*)(out + (long)row * OUT_F + f0) = make_float2(acc0, acc1);
        }
    }
}

extern "C" void kernel_launch(void* const* d_in, const int* in_sizes, int n_in,
                              void* d_out, int out_size, void* d_ws, size_t ws_size,
                              hipStream_t stream) {
    const float* x    = (const float*)d_in[0];
    const int*   row0 = (const int*)d_in[1];
    const int*   col0 = (const int*)d_in[2];
    const float* val0 = (const float*)d_in[3];
    const int*   row1 = (const int*)d_in[4];
    const int*   col1 = (const int*)d_in[5];
    const float* val1 = (const float*)d_in[6];
    const float* W0   = (const float*)d_in[7];
    const float* b0   = (const float*)d_in[8];
    const float* W1   = (const float*)d_in[9];
    const float* b1   = (const float*)d_in[10];
    float* out = (float*)d_out;

    // Workspace: sup0 (12.8 MB), sup1 (6.4 MB), bcv0/1 (9.6 MB each),
    // gfill, wt0, wt1.  Total ~39 MB.
    __half* sup0 = (__half*)d_ws;
    __half* sup1 = sup0 + (long)N_NODES * HID_F;
    int2* bcv0   = (int2*)(sup1 + (long)N_NODES * OUT_F);
    int2* bcv1   = bcv0 + (long)NBUCK * BCAP;
    int*  gfill  = (int*)(bcv1 + (long)NBUCK * BCAP);
    __half* wt0  = (__half*)(gfill + 2 * NBUCK + 2);   // [HID_F][IN_F]
    __half* wt1  = wt0 + IN_F * HID_F;                 // [OUT_F][HID_F]

    // ---- Prep (zero gfill + weight transpose) ----
    prep_kernel<<<(IN_F * HID_F + 255) / 256, 256, 0, stream>>>(W0, W1, wt0, wt1, gfill);

    // ---- bin graph0 || layer-0 GEMM ----
    bin0_gemm_kernel<<<dim3(G0_NB, 2), BIN_T, 0, stream>>>(
        row0, col0, val0, gfill, bcv0, x, wt0, sup0, N_NODES);

    // ---- agg+relu+gemm1 || bin graph1 (bin1 leaves the critical path) ----
    agg_bin1_kernel<<<dim3(NBUCK, 2), 256, 0, stream>>>(
        gfill, bcv0, bcv1, row1, col1, val1, sup0, b0, wt1, sup1);

    // ---- Layer-1 aggregate ----
    spmm_l1_kernel<<<NBUCK, 256, 0, stream>>>(gfill, bcv1, sup1, b1, out);
}

// Round 13
// 178.264 us; speedup vs baseline: 1.0519x; 1.0519x over previous
//
#include <hip/hip_runtime.h>
#include <hip/hip_fp16.h>

#define N_NODES 50000
#define IN_F    128
#define HID_F   128
#define OUT_F   64
#define E_EDGES 800000

// Fine buckets: 16 rows = one aggregation block; consumer counting-sorts its
// ~256 edges in LDS then register-accumulates.  Measured lessons:
//  - r5: per-row global scatter = 64B/edge writeback (94us). Bin runs stay
//    bucket-contiguous.
//  - r9: LDS f32 atomicAdd scatter = 102M ds_add = 588us. Registers only.
//  - r7: deeper batches lose to VGPR/occupancy; widen loads instead.
//  - r10: in-consumer sort beats separate sort dispatch (181->178). BASE.
//  - r12: co-dispatching long-block bin1 with agg serializes (+20us on the
//    dispatch); riders must be short-blocked. Bins stay with gemm0.
// This round: ONE lever vs r10 — agg phase-1 half-wave hv4 (8B) gathers,
// 16 rows in flight per wave at the same 8-deep batch.
#define RPB   16
#define NBUCK ((N_NODES + RPB - 1) / RPB)            // 3125
#define BCAP  384                                    // mean 256, +8 sigma
#define BIN_T   512
#define BIN_EPT 16
#define BIN_EPB (BIN_T * BIN_EPT)                    // 8192 edges per block
#define BIN_NB  ((E_EDGES + BIN_EPB - 1) / BIN_EPB)  // 98
#define G0_NB   ((N_NODES + 127) / 128)              // 391 gemm0 blocks
#define HP      (HID_F + 8)                          // ht stride (272B, 16-aligned)

typedef _Float16 half8 __attribute__((ext_vector_type(8)));
typedef _Float16 hv4   __attribute__((ext_vector_type(4)));
typedef float    floatx4 __attribute__((ext_vector_type(4)));

// ---------------- Prep: zero gfill + convert W0/W1 to fp16 transposed -------
__global__ __launch_bounds__(256) void prep_kernel(const float* __restrict__ W0,
                                                   const float* __restrict__ W1,
                                                   __half* __restrict__ wt0,
                                                   __half* __restrict__ wt1,
                                                   int* __restrict__ gfill) {
    int tid = blockIdx.x * 256 + threadIdx.x;
    if (tid < IN_F * HID_F) {               // wt0[n][k] = W0[k][n], 128x128
        int k = tid >> 7, n = tid & 127;
        wt0[n * IN_F + k] = __float2half(W0[tid]);
    }
    if (tid < HID_F * OUT_F) {              // wt1[n][k] = W1[k][n], 128x64
        int k = tid / OUT_F, n = tid % OUT_F;
        wt1[n * HID_F + k] = __float2half(W1[tid]);
    }
    if (tid < 2 * NBUCK) gfill[tid] = 0;
}

// ---------------- Bin (y=0,1) + layer-0 GEMM (y=2) in one dispatch ----------
union BinLds {
    struct { int lhist[NBUCK]; int lbase[NBUCK]; } h;   // 25 KB
    _Float16 ws[HID_F * (IN_F + 8)];                    // 34.8 KB (dominates)
};

__global__ __launch_bounds__(BIN_T) void bin_gemm_kernel(
        const int* __restrict__ row0, const int* __restrict__ col0, const float* __restrict__ val0,
        const int* __restrict__ row1, const int* __restrict__ col1, const float* __restrict__ val1,
        int* __restrict__ gfill, int2* __restrict__ bcv0, int2* __restrict__ bcv1,
        const float* __restrict__ x, const __half* __restrict__ wt0,
        __half* __restrict__ sup0, int M) {
    __shared__ BinLds lds;
    const int tid = threadIdx.x;

    if (blockIdx.y < 2) {
        // ---------------- bucket binning ----------------
        if (blockIdx.x >= BIN_NB) return;
        const int g = blockIdx.y;
        const int*   rowi = g ? row1 : row0;
        const int*   coli = g ? col1 : col0;
        const float* vali = g ? val1 : val0;
        int*  gf  = gfill + g * NBUCK;
        int2* bcv = g ? bcv1 : bcv0;

        for (int i = tid; i < NBUCK; i += BIN_T) lds.h.lhist[i] = 0;
        __syncthreads();

        int rnk[BIN_EPT], bkt[BIN_EPT], cl[BIN_EPT], rw[BIN_EPT];
        float vl[BIN_EPT];
        const int e0 = blockIdx.x * BIN_EPB;
#pragma unroll
        for (int i = 0; i < BIN_EPT; ++i) {
            const int e = e0 + i * BIN_T + tid;
            bkt[i] = -1;
            if (e < E_EDGES) {
                const int r = rowi[e];
                rw[i] = r; cl[i] = coli[e]; vl[i] = vali[e];
                bkt[i] = r >> 4;                       // bucket = r / RPB
                rnk[i] = atomicAdd(&lds.h.lhist[bkt[i]], 1);
            }
        }
        __syncthreads();
        for (int i = tid; i < NBUCK; i += BIN_T) {
            const int c = lds.h.lhist[i];
            lds.h.lbase[i] = c ? atomicAdd(&gf[i], c) : 0;
        }
        __syncthreads();
#pragma unroll
        for (int i = 0; i < BIN_EPT; ++i) {
            if (bkt[i] >= 0) {
                const int pos = lds.h.lbase[bkt[i]] + rnk[i];
                if (pos < BCAP)
                    bcv[(long)bkt[i] * BCAP + pos] =
                        make_int2(((rw[i] & (RPB - 1)) << 16) | cl[i], __float_as_int(vl[i]));
            }
        }
    } else {
        // ---------------- layer-0 GEMM: 128 rows per block ----------
        constexpr int KP = IN_F + 8;
        constexpr int NT = HID_F / 16;
        for (int c = tid; c < HID_F * (IN_F / 8); c += BIN_T) {
            const int n = c / (IN_F / 8), ko = (c % (IN_F / 8)) * 8;
            *(half8*)&lds.ws[n * KP + ko] = *(const half8*)(wt0 + n * IN_F + ko);
        }
        __syncthreads();

        const int wv = tid >> 6, lane = tid & 63;
        const int quad = lane >> 4, l16 = lane & 15;
        const int rowb = blockIdx.x * 128 + wv * 16;
        const int arow = rowb + l16;

        floatx4 acc[NT] = {};
#pragma unroll
        for (int ks = 0; ks < IN_F; ks += 32) {
            half8 af = {};
            if (arow < M) {
                const float4* p = (const float4*)(x + (long)arow * IN_F + ks + quad * 8);
                float4 u = p[0], w = p[1];
                af[0] = (_Float16)u.x; af[1] = (_Float16)u.y;
                af[2] = (_Float16)u.z; af[3] = (_Float16)u.w;
                af[4] = (_Float16)w.x; af[5] = (_Float16)w.y;
                af[6] = (_Float16)w.z; af[7] = (_Float16)w.w;
            }
#pragma unroll
            for (int t = 0; t < NT; ++t) {
                half8 bf = *(const half8*)&lds.ws[(t * 16 + l16) * KP + ks + quad * 8];
                acc[t] = __builtin_amdgcn_mfma_f32_16x16x32_f16(af, bf, acc[t], 0, 0, 0);
            }
        }
#pragma unroll
        for (int t = 0; t < NT; ++t) {
            const int col = t * 16 + l16;
#pragma unroll
            for (int i = 0; i < 4; ++i) {
                const int row = rowb + quad * 4 + i;
                if (row < M) sup0[(long)row * HID_F + col] = __float2half(acc[t][i]);
            }
        }
    }
}

// ---------------- Fused: LDS sort + layer-0 aggregate + relu + gemm1 -------
// Block = bucket = 16 rows, ~256 edges. Counting sort in LDS, then phase-1
// with HALF-WAVE per edge + hv4 (8B) gathers: 16 rows in flight per wave at
// the 8-deep batch (the single lever vs r10's full-wave __half2 version).
__global__ __launch_bounds__(256) void agg_gemm_kernel(const int* __restrict__ gfill,
                                                       const int2* __restrict__ bcv,
                                                       const __half* __restrict__ sup,
                                                       const float* __restrict__ bias,
                                                       const __half* __restrict__ wt1,
                                                       __half* __restrict__ sup1) {
    __shared__ int2 sbuf[BCAP];       // 3 KB sorted edges
    __shared__ int  cur[RPB];
    __shared__ int  st[RPB + 1];
    __shared__ _Float16 ht[16 * HP];  // 4.4 KB
    const int tid  = threadIdx.x;
    const int wv   = tid >> 6;
    const int lane = tid & 63;
    const int eh   = lane >> 5;
    const int li   = lane & 31;
    const int b    = blockIdx.x;
    const int cnt  = min(gfill[b], BCAP);
    const int2* eb = bcv + (long)b * BCAP;

    // ---- LDS counting sort of the bucket's edges by local row ----
    int2 ed[2]; int rnk[2];
    if (tid < RPB) cur[tid] = 0;
    __syncthreads();
#pragma unroll
    for (int k = 0; k < 2; ++k) {
        const int e = tid + k * 256;
        if (e < cnt) {
            ed[k] = eb[e];
            rnk[k] = atomicAdd(&cur[ed[k].x >> 16], 1);
        }
    }
    __syncthreads();
    if (tid == 0) {
        int s = 0;
#pragma unroll
        for (int i = 0; i < RPB; ++i) { st[i] = s; s += cur[i]; }
        st[RPB] = s;
    }
    __syncthreads();
#pragma unroll
    for (int k = 0; k < 2; ++k) {
        const int e = tid + k * 256;
        if (e < cnt) sbuf[st[ed[k].x >> 16] + rnk[k]] = ed[k];
    }
    __syncthreads();

    // ---- Phase 1: wave wv -> rows wv*4..+3; half-waves take even/odd edges;
    //      lane owns 4 features, hv4 8B gathers (16 rows in flight per wave)
#pragma unroll
    for (int i = 0; i < 4; ++i) {
        const int r  = wv * 4 + i;
        const int s0 = st[r], s1 = st[r + 1];
        float a0, a1, a2, a3;
        if (eh == 0) {
            a0 = bias[li * 4];     a1 = bias[li * 4 + 1];
            a2 = bias[li * 4 + 2]; a3 = bias[li * 4 + 3];
        } else a0 = a1 = a2 = a3 = 0.f;
        for (int j = s0; j < s1; j += 16) {
            int   pr[8];
            float v[8];
#pragma unroll
            for (int q = 0; q < 8; ++q) {              // broadcast LDS reads
                const int idx = j + 2 * q + eh;
                if (idx < s1) {
                    int2 e2 = sbuf[idx];
                    pr[q] = e2.x & 0xFFFF;
                    v[q]  = __int_as_float(e2.y);
                } else { pr[q] = 0; v[q] = 0.f; }      // masked: row 0, v=0
            }
            hv4 s8[8];
#pragma unroll
            for (int q = 0; q < 8; ++q)                // 8x 8B gathers in flight
                s8[q] = *(const hv4*)(sup + (long)pr[q] * HID_F + li * 4);
#pragma unroll
            for (int q = 0; q < 8; ++q) {
                a0 += v[q] * (float)s8[q][0];
                a1 += v[q] * (float)s8[q][1];
                a2 += v[q] * (float)s8[q][2];
                a3 += v[q] * (float)s8[q][3];
            }
        }
        a0 += __shfl_xor(a0, 32, 64);
        a1 += __shfl_xor(a1, 32, 64);
        a2 += __shfl_xor(a2, 32, 64);
        a3 += __shfl_xor(a3, 32, 64);
        if (eh == 0) {
            hv4 h;
            h[0] = (_Float16)(a0 > 0.f ? a0 : 0.f);    // relu
            h[1] = (_Float16)(a1 > 0.f ? a1 : 0.f);
            h[2] = (_Float16)(a2 > 0.f ? a2 : 0.f);
            h[3] = (_Float16)(a3 > 0.f ? a3 : 0.f);
            *(hv4*)&ht[r * HP + li * 4] = h;
        }
    }
    __syncthreads();

    // ---- Phase 2: 16x64 gemm1 tile, wave wv -> cols wv*16..+15 ----
    const int quad = lane >> 4, l16 = lane & 15;
    floatx4 oacc = {};
#pragma unroll
    for (int ks = 0; ks < HID_F; ks += 32) {
        half8 af = *(const half8*)&ht[l16 * HP + ks + quad * 8];
        half8 bf = *(const half8*)(wt1 + (long)(wv * 16 + l16) * HID_F + ks + quad * 8);
        oacc = __builtin_amdgcn_mfma_f32_16x16x32_f16(af, bf, oacc, 0, 0, 0);
    }
    const int r0 = b * 16;
#pragma unroll
    for (int i = 0; i < 4; ++i) {
        const int row = r0 + quad * 4 + i;
        sup1[(long)row * OUT_F + wv * 16 + l16] = __float2half(oacc[i]);
    }
}

// ---------------- SpMM layer 1: LDS sort + half-wave register aggregate ----
__global__ __launch_bounds__(256) void spmm_l1_kernel(const int* __restrict__ gfill,
                                                      const int2* __restrict__ bcv,
                                                      const __half* __restrict__ sup,
                                                      const float* __restrict__ bias,
                                                      float* __restrict__ out) {
    __shared__ int2 sbuf[BCAP];
    __shared__ int  cur[RPB];
    __shared__ int  st[RPB + 1];
    const int tid  = threadIdx.x;
    const int wv   = tid >> 6;
    const int lane = tid & 63;
    const int b    = blockIdx.x;
    const int cnt  = min(gfill[NBUCK + b], BCAP);
    const int2* eb = bcv + (long)b * BCAP;
    const int eh = lane >> 5;
    const int li = lane & 31;
    const int f0 = li * 2;

    // ---- LDS counting sort ----
    int2 ed[2]; int rnk[2];
    if (tid < RPB) cur[tid] = 0;
    __syncthreads();
#pragma unroll
    for (int k = 0; k < 2; ++k) {
        const int e = tid + k * 256;
        if (e < cnt) {
            ed[k] = eb[e];
            rnk[k] = atomicAdd(&cur[ed[k].x >> 16], 1);
        }
    }
    __syncthreads();
    if (tid == 0) {
        int s = 0;
#pragma unroll
        for (int i = 0; i < RPB; ++i) { st[i] = s; s += cur[i]; }
        st[RPB] = s;
    }
    __syncthreads();
#pragma unroll
    for (int k = 0; k < 2; ++k) {
        const int e = tid + k * 256;
        if (e < cnt) sbuf[st[ed[k].x >> 16] + rnk[k]] = ed[k];
    }
    __syncthreads();

    // ---- wave wv -> rows wv*4..+3; half-waves split even/odd edges ----
#pragma unroll
    for (int i = 0; i < 4; ++i) {
        const int r  = wv * 4 + i;
        const int s0 = st[r], s1 = st[r + 1];
        float acc0 = eh ? 0.f : bias[f0];
        float acc1 = eh ? 0.f : bias[f0 + 1];
        for (int j = s0; j < s1; j += 16) {
            int   pr[8];
            float v[8];
#pragma unroll
            for (int q = 0; q < 8; ++q) {
                const int idx = j + 2 * q + eh;
                if (idx < s1) {
                    int2 e2 = sbuf[idx];
                    pr[q] = e2.x & 0xFFFF;
                    v[q]  = __int_as_float(e2.y);
                } else { pr[q] = 0; v[q] = 0.f; }
            }
            __half2 s8[8];
#pragma unroll
            for (int q = 0; q < 8; ++q)
                s8[q] = *(const __half2*)(sup + (long)pr[q] * OUT_F + f0);
#pragma unroll
            for (int q = 0; q < 8; ++q) {
                float2 g = __half22float2(s8[q]);
                acc0 += v[q] * g.x; acc1 += v[q] * g.y;
            }
        }
        acc0 += __shfl_xor(acc0, 32, 64);
        acc1 += __shfl_xor(acc1, 32, 64);
        if (eh == 0) {
            const int row = b * 16 + r;
            *(float2*)(out + (long)row * OUT_F + f0) = make_float2(acc0, acc1);
        }
    }
}

extern "C" void kernel_launch(void* const* d_in, const int* in_sizes, int n_in,
                              void* d_out, int out_size, void* d_ws, size_t ws_size,
                              hipStream_t stream) {
    const float* x    = (const float*)d_in[0];
    const int*   row0 = (const int*)d_in[1];
    const int*   col0 = (const int*)d_in[2];
    const float* val0 = (const float*)d_in[3];
    const int*   row1 = (const int*)d_in[4];
    const int*   col1 = (const int*)d_in[5];
    const float* val1 = (const float*)d_in[6];
    const float* W0   = (const float*)d_in[7];
    const float* b0   = (const float*)d_in[8];
    const float* W1   = (const float*)d_in[9];
    const float* b1   = (const float*)d_in[10];
    float* out = (float*)d_out;

    // Workspace: sup0 (12.8 MB), sup1 (6.4 MB), bcv0/1 (9.6 MB each),
    // gfill, wt0, wt1.  Total ~39 MB.
    __half* sup0 = (__half*)d_ws;
    __half* sup1 = sup0 + (long)N_NODES * HID_F;
    int2* bcv0   = (int2*)(sup1 + (long)N_NODES * OUT_F);
    int2* bcv1   = bcv0 + (long)NBUCK * BCAP;
    int*  gfill  = (int*)(bcv1 + (long)NBUCK * BCAP);
    __half* wt0  = (__half*)(gfill + 2 * NBUCK + 2);   // [HID_F][IN_F]
    __half* wt1  = wt0 + IN_F * HID_F;                 // [OUT_F][HID_F]

    // ---- Prep (zero gfill + weight transpose) ----
    prep_kernel<<<(IN_F * HID_F + 255) / 256, 256, 0, stream>>>(W0, W1, wt0, wt1, gfill);

    // ---- Bin (both graphs) || layer-0 GEMM, one dispatch (r10 structure) ----
    bin_gemm_kernel<<<dim3(G0_NB, 3), BIN_T, 0, stream>>>(
        row0, col0, val0, row1, col1, val1, gfill, bcv0, bcv1,
        x, wt0, sup0, N_NODES);

    // ---- Fused: LDS-sort + layer-0 aggregate + bias/relu + layer-1 GEMM ----
    agg_gemm_kernel<<<NBUCK, 256, 0, stream>>>(gfill, bcv0, sup0, b0, wt1, sup1);

    // ---- Layer-1 aggregate (LDS-sort + register acc) ----
    spmm_l1_kernel<<<NBUCK, 256, 0, stream>>>(gfill, bcv1, sup1, b1, out);
}